// Round 4
// baseline (219.229 us; speedup 1.0000x reference)
//
#include <hip/hip_runtime.h>

// BahdanauAttention on MI355X — fp32 in/out. NO d_ws usage (round-3 post-
// timing divergence traced to writing 4MB of scratch into d_ws without
// checking ws_size; scratch now lives inside d_out's ctx region).
//
// d_out float layout: ctx [0, 1048576), attn [1048576, 1310720).
// During phases 1-2 the ctx region holds scratch:
//   qe  at [0,      524288): [1024][512]   e^{2*qproj}
//   kep at [524288,1048576): [4][512][256] e^{2*kproj} * ie2[u], ie2=0.5/scale
// Phase 3 (k2b) overwrites ctx region with the final context.
//
// Math: tanh(x) = 1 - 2/(e^{2x}+1); score = S - sum_u 2*scale_u/(E+1),
// S = sum(scale) cancels in softmax. term = rcp(qe*kep + ie2).

// ---------- K1: fp32 VALU projections + exp epilogue -----------------------
// grid (2, 128, 2), block 256. Block: 8 rows x 256 u-cols. Thread: 2 rows x 4 u.
__global__ __launch_bounds__(256) void k1_proj(
    const float* __restrict__ query, const float* __restrict__ value,
    const float* __restrict__ Wq, const float* __restrict__ Wk,
    const float* __restrict__ scale, float* __restrict__ outbuf) {
  const int z = blockIdx.z;
  const float4* X4 = (const float4*)(z ? value : query);
  const float4* W4 = (const float4*)(z ? Wk : Wq);  // [1024][128] float4
  const int lane = threadIdx.x & 63, wv = threadIdx.x >> 6;
  const int u4 = blockIdx.x * 64 + lane;   // float4 col in [0,128)
  const int m0 = blockIdx.y * 8 + wv * 2;  // even row in [0,1024)
  const float4* X0 = X4 + m0 * 256;
  const float4* X1 = X4 + (m0 + 1) * 256;
  float a0[4] = {0.f, 0.f, 0.f, 0.f}, a1[4] = {0.f, 0.f, 0.f, 0.f};
#pragma unroll 2
  for (int d4 = 0; d4 < 256; ++d4) {
    float4 x0 = X0[d4], x1 = X1[d4];          // wave-uniform broadcasts
    float4 w0 = W4[(4 * d4 + 0) * 128 + u4];  // coalesced 1KB/wave
    float4 w1 = W4[(4 * d4 + 1) * 128 + u4];
    float4 w2 = W4[(4 * d4 + 2) * 128 + u4];
    float4 w3 = W4[(4 * d4 + 3) * 128 + u4];
    a0[0] = fmaf(x0.x, w0.x, a0[0]); a0[1] = fmaf(x0.x, w0.y, a0[1]);
    a0[2] = fmaf(x0.x, w0.z, a0[2]); a0[3] = fmaf(x0.x, w0.w, a0[3]);
    a0[0] = fmaf(x0.y, w1.x, a0[0]); a0[1] = fmaf(x0.y, w1.y, a0[1]);
    a0[2] = fmaf(x0.y, w1.z, a0[2]); a0[3] = fmaf(x0.y, w1.w, a0[3]);
    a0[0] = fmaf(x0.z, w2.x, a0[0]); a0[1] = fmaf(x0.z, w2.y, a0[1]);
    a0[2] = fmaf(x0.z, w2.z, a0[2]); a0[3] = fmaf(x0.z, w2.w, a0[3]);
    a0[0] = fmaf(x0.w, w3.x, a0[0]); a0[1] = fmaf(x0.w, w3.y, a0[1]);
    a0[2] = fmaf(x0.w, w3.z, a0[2]); a0[3] = fmaf(x0.w, w3.w, a0[3]);
    a1[0] = fmaf(x1.x, w0.x, a1[0]); a1[1] = fmaf(x1.x, w0.y, a1[1]);
    a1[2] = fmaf(x1.x, w0.z, a1[2]); a1[3] = fmaf(x1.x, w0.w, a1[3]);
    a1[0] = fmaf(x1.y, w1.x, a1[0]); a1[1] = fmaf(x1.y, w1.y, a1[1]);
    a1[2] = fmaf(x1.y, w1.z, a1[2]); a1[3] = fmaf(x1.y, w1.w, a1[3]);
    a1[0] = fmaf(x1.z, w2.x, a1[0]); a1[1] = fmaf(x1.z, w2.y, a1[1]);
    a1[2] = fmaf(x1.z, w2.z, a1[2]); a1[3] = fmaf(x1.z, w2.w, a1[3]);
    a1[0] = fmaf(x1.w, w3.x, a1[0]); a1[1] = fmaf(x1.w, w3.y, a1[1]);
    a1[2] = fmaf(x1.w, w3.z, a1[2]); a1[3] = fmaf(x1.w, w3.w, a1[3]);
  }
  float* qe = outbuf;             // [1024][512]
  float* kep = outbuf + 524288;   // [4][512][256]
  if (z == 0) {
    float4 e0, e1;
    e0.x = __expf(2.f * a0[0]); e0.y = __expf(2.f * a0[1]);
    e0.z = __expf(2.f * a0[2]); e0.w = __expf(2.f * a0[3]);
    e1.x = __expf(2.f * a1[0]); e1.y = __expf(2.f * a1[1]);
    e1.z = __expf(2.f * a1[2]); e1.w = __expf(2.f * a1[3]);
    ((float4*)(qe + m0 * 512))[u4] = e0;
    ((float4*)(qe + (m0 + 1) * 512))[u4] = e1;
  } else {
    const int b = m0 >> 8, kl = m0 & 255;  // rows m0,m0+1 share b (m0 even)
#pragma unroll
    for (int c = 0; c < 4; ++c) {
      int u = 4 * u4 + c;
      float i2 = 0.5f / scale[u];
      kep[b * 131072 + u * 256 + kl] = __expf(2.f * a0[c]) * i2;
      kep[b * 131072 + u * 256 + kl + 1] = __expf(2.f * a1[c]) * i2;
    }
  }
}

// ---------- K2a: scores + softmax -> attn region only ----------------------
// 1 block = (b, 4 q rows). grid 256, block 512.
__global__ __launch_bounds__(512) void k2a_attn(
    const float* __restrict__ qe, const float* __restrict__ kep,
    const float* __restrict__ scale, float* __restrict__ attn) {
  const int b = blockIdx.x >> 6;
  const int qbase = (blockIdx.x & 63) * 4;
  const int tid = threadIdx.x;
  __shared__ __align__(16) float qh[512 * 2 * 4];  // [u][half]{qe0,qe1,ie2,pad}
  __shared__ __align__(16) float ps[256 * 4];      // [k][qi]

  for (int idx = tid; idx < 1024; idx += 512) {
    int u = idx >> 1, h = idx & 1;
    float* p = &qh[(u * 2 + h) * 4];
    p[0] = qe[(b * 256 + qbase + 2 * h) * 512 + u];
    p[1] = qe[(b * 256 + qbase + 2 * h + 1) * 512 + u];
    p[2] = 0.5f / scale[u];
    p[3] = 0.f;
  }
  __syncthreads();

  const int k = tid & 255, half = tid >> 8;
  const float* kb = kep + b * 131072;
  const float4* qhv = (const float4*)qh;
  float s0 = 0.f, s1 = 0.f;
#pragma unroll 8
  for (int u = 0; u < 512; ++u) {
    float kv = kb[u * 256 + k];     // coalesced, L2-resident
    float4 qq = qhv[u * 2 + half];  // wave-uniform LDS broadcast
    s0 += __builtin_amdgcn_rcpf(fmaf(qq.x, kv, qq.z));
    s1 += __builtin_amdgcn_rcpf(fmaf(qq.y, kv, qq.z));
  }
  ps[k * 4 + 2 * half] = s0;  // softmax score = -acc (S cancels)
  ps[k * 4 + 2 * half + 1] = s1;
  __syncthreads();

  const int w = tid >> 6, lane = tid & 63;
  if (w < 4) {  // wave w: softmax for q-row qbase+w
    float x0 = -ps[(lane)*4 + w], x1 = -ps[(lane + 64) * 4 + w];
    float x2 = -ps[(lane + 128) * 4 + w], x3 = -ps[(lane + 192) * 4 + w];
    float m = fmaxf(fmaxf(x0, x1), fmaxf(x2, x3));
    for (int off = 32; off; off >>= 1) m = fmaxf(m, __shfl_xor(m, off));
    float e0 = __expf(x0 - m), e1 = __expf(x1 - m);
    float e2 = __expf(x2 - m), e3 = __expf(x3 - m);
    float t = e0 + e1 + e2 + e3;
    for (int off = 32; off; off >>= 1) t += __shfl_xor(t, off);
    float inv = 1.0f / t;
    float* ar = attn + (b * 256 + qbase + w) * 256;
    ar[lane] = e0 * inv;
    ar[lane + 64] = e1 * inv;
    ar[lane + 128] = e2 * inv;
    ar[lane + 192] = e3 * inv;
  }
}

// ---------- K2b: ctx = attn @ value, overwrites ctx region -----------------
// grid (2, 32, 4): dh-half of d, 8 q-rows, batch. block 256.
__global__ __launch_bounds__(256) void k2b_ctx(
    const float* __restrict__ attn, const float* __restrict__ value,
    float* __restrict__ ctx) {
  const int dh = blockIdx.x, q0 = blockIdx.y * 8, b = blockIdx.z;
  const int tid = threadIdx.x;
  __shared__ __align__(16) float pl[256 * 8];  // [k][r]
#pragma unroll
  for (int r = 0; r < 8; ++r)
    pl[tid * 8 + r] = attn[(b * 256 + q0 + r) * 256 + tid];
  __syncthreads();
  const float2* v2 = (const float2*)value + b * 131072 + dh * 256 + tid;
  const float4* pl4 = (const float4*)pl;
  float2 acc[8];
#pragma unroll
  for (int r = 0; r < 8; ++r) acc[r] = make_float2(0.f, 0.f);
#pragma unroll 4
  for (int kk = 0; kk < 256; ++kk) {
    float2 v = v2[kk * 512];
    float4 pa = pl4[kk * 2], pb = pl4[kk * 2 + 1];  // LDS broadcast b128
    acc[0].x = fmaf(pa.x, v.x, acc[0].x); acc[0].y = fmaf(pa.x, v.y, acc[0].y);
    acc[1].x = fmaf(pa.y, v.x, acc[1].x); acc[1].y = fmaf(pa.y, v.y, acc[1].y);
    acc[2].x = fmaf(pa.z, v.x, acc[2].x); acc[2].y = fmaf(pa.z, v.y, acc[2].y);
    acc[3].x = fmaf(pa.w, v.x, acc[3].x); acc[3].y = fmaf(pa.w, v.y, acc[3].y);
    acc[4].x = fmaf(pb.x, v.x, acc[4].x); acc[4].y = fmaf(pb.x, v.y, acc[4].y);
    acc[5].x = fmaf(pb.y, v.x, acc[5].x); acc[5].y = fmaf(pb.y, v.y, acc[5].y);
    acc[6].x = fmaf(pb.z, v.x, acc[6].x); acc[6].y = fmaf(pb.z, v.y, acc[6].y);
    acc[7].x = fmaf(pb.w, v.x, acc[7].x); acc[7].y = fmaf(pb.w, v.y, acc[7].y);
  }
  float2* c2 = (float2*)ctx;
#pragma unroll
  for (int r = 0; r < 8; ++r)
    c2[(b * 256 + q0 + r) * 512 + dh * 256 + tid] = acc[r];
}

extern "C" void kernel_launch(void* const* d_in, const int* in_sizes, int n_in,
                              void* d_out, int out_size, void* d_ws, size_t ws_size,
                              hipStream_t stream) {
  (void)d_ws; (void)ws_size;  // deliberately unused — see header comment
  const float *query = nullptr, *value = nullptr, *Wq = nullptr, *Wk = nullptr,
              *scale = nullptr;
  for (int i = 0; i < n_in; ++i) {
    int s = in_sizes[i];
    if (s == 1048576) { if (!query) query = (const float*)d_in[i]; else if (!value) value = (const float*)d_in[i]; }
    else if (s == 524288) { if (!Wq) Wq = (const float*)d_in[i]; else if (!Wk) Wk = (const float*)d_in[i]; }
    else if (s == 512) { scale = (const float*)d_in[i]; }
  }
  float* ob = (float*)d_out;
  k1_proj<<<dim3(2, 128, 2), 256, 0, stream>>>(query, value, Wq, Wk, scale, ob);
  k2a_attn<<<dim3(256), 512, 0, stream>>>(ob, ob + 524288, scale, ob + 1048576);
  k2b_ctx<<<dim3(2, 32, 4), 256, 0, stream>>>(ob + 1048576, value, ob);
}

// Round 5
// 151.703 us; speedup vs baseline: 1.4451x; 1.4451x over previous
//
#include <hip/hip_runtime.h>

// BahdanauAttention on MI355X — fp32 in/out. Scratch inside d_out (no d_ws:
// round-3 post-timing divergence was d_ws overflow corrupting harness state).
//
// d_out float layout: ctx [0, 1048576), attn [1048576, 1310720).
// Phases 1-2 use ctx region as scratch:
//   qe  at [0,      524288): [1024][512]   e^{2*qproj}
//   kep at [524288,1048576): [4][512][256] e^{2*kproj} * ie2[u], ie2=0.5/scale
// Phase 3 (k2b) overwrites ctx region with the final context.
//
// Math: tanh(x) = 1 - 2/(e^{2x}+1); score = S - sum_u 2*scale_u/(E+1),
// S = sum(scale) cancels in softmax. term = rcp(qe*kep + ie2) = 2*scale/(E+1).
//
// k1: MFMA bf16 with EXACT hi/lo split (x = hi + lo, lo = x - trunc_bf16(x)):
// x@w ~ hi_x*hi_w + hi_x*lo_w + lo_x*hi_w  (dropped lo*lo ~ 2^-18) -> fp32-
// equivalent accuracy at 3x (cheap) MFMA cost. // block=256: 64x64 tile,
// 4 waves of 32x32, K-step 32.

typedef unsigned int u32;
typedef unsigned short u16;
typedef __attribute__((ext_vector_type(8))) short s16x8;
typedef __attribute__((ext_vector_type(4))) float f32x4;

// ---------- K1: split-bf16 MFMA projections + exp epilogue -----------------
// grid (8, 16, 2), block 256. z=0: query->qe ; z=1: value->kep (transposed).
__global__ __launch_bounds__(256) void k1_mfma(
    const float* __restrict__ query, const float* __restrict__ value,
    const float* __restrict__ Wq, const float* __restrict__ Wk,
    const float* __restrict__ scale, float* __restrict__ outbuf) {
  const int z = blockIdx.z;
  const float* X = z ? value : query;  // [1024][1024]
  const float* W = z ? Wk : Wq;        // [1024][512]
  const int M0 = blockIdx.y * 64, N0 = blockIdx.x * 64;
  // row stride 40 bf16 (80 B): 16B-aligned b128 rows, breaks pow2 bank aliasing
  __shared__ __align__(16) u16 AsH[64 * 40], AsL[64 * 40];
  __shared__ __align__(16) u16 BsH[64 * 40], BsL[64 * 40];
  const int tid = threadIdx.x;
  const int lane = tid & 63, w = tid >> 6;
  const int quad = lane >> 4, r16 = lane & 15;
  const int m0w = (w & 1) * 32, n0w = (w >> 1) * 32;
  f32x4 acc00 = {0.f, 0.f, 0.f, 0.f};
  f32x4 acc01 = acc00, acc10 = acc00, acc11 = acc00;
  const int arow = tid >> 2, aseg = tid & 3;  // A: 64 rows x 4 segs of 8
  const int bu = tid & 63, bks = tid >> 6;    // B: 64 u-rows x 4 k-segs of 8

  for (int kb = 0; kb < 1024; kb += 32) {
    // ---- stage A tile (64 m x 32 k), exact hi/lo split ----
    {
      const float4* ap = (const float4*)(X + (M0 + arow) * 1024 + kb + aseg * 8);
      float4 xa = ap[0], xb = ap[1];
      float fs[8] = {xa.x, xa.y, xa.z, xa.w, xb.x, xb.y, xb.z, xb.w};
      u32 hi[4], lo[4];
#pragma unroll
      for (int p = 0; p < 4; ++p) {
        u32 u0 = __float_as_uint(fs[2 * p]);
        u32 u1 = __float_as_uint(fs[2 * p + 1]);
        hi[p] = (u0 >> 16) | (u1 & 0xffff0000u);
        float l0 = fs[2 * p] - __uint_as_float(u0 & 0xffff0000u);
        float l1 = fs[2 * p + 1] - __uint_as_float(u1 & 0xffff0000u);
        lo[p] = (__float_as_uint(l0) >> 16) | (__float_as_uint(l1) & 0xffff0000u);
      }
      *(uint4*)(AsH + arow * 40 + aseg * 8) = make_uint4(hi[0], hi[1], hi[2], hi[3]);
      *(uint4*)(AsL + arow * 40 + aseg * 8) = make_uint4(lo[0], lo[1], lo[2], lo[3]);
    }
    // ---- stage B tile (32 k x 64 u -> Bs[u][k]), exact hi/lo split ----
    {
      float fs[8];
#pragma unroll
      for (int j = 0; j < 8; ++j)
        fs[j] = W[(kb + bks * 8 + j) * 512 + N0 + bu];  // coalesced per-k row
      u32 hi[4], lo[4];
#pragma unroll
      for (int p = 0; p < 4; ++p) {
        u32 u0 = __float_as_uint(fs[2 * p]);
        u32 u1 = __float_as_uint(fs[2 * p + 1]);
        hi[p] = (u0 >> 16) | (u1 & 0xffff0000u);
        float l0 = fs[2 * p] - __uint_as_float(u0 & 0xffff0000u);
        float l1 = fs[2 * p + 1] - __uint_as_float(u1 & 0xffff0000u);
        lo[p] = (__float_as_uint(l0) >> 16) | (__float_as_uint(l1) & 0xffff0000u);
      }
      *(uint4*)(BsH + bu * 40 + bks * 8) = make_uint4(hi[0], hi[1], hi[2], hi[3]);
      *(uint4*)(BsL + bu * 40 + bks * 8) = make_uint4(lo[0], lo[1], lo[2], lo[3]);
    }
    __syncthreads();
    // ---- fragments + 12 MFMA (hi*hi, hi*lo, lo*hi for 2x2 tile) ----
    s16x8 aH0 = *(const s16x8*)(AsH + (m0w + r16) * 40 + quad * 8);
    s16x8 aH1 = *(const s16x8*)(AsH + (m0w + 16 + r16) * 40 + quad * 8);
    s16x8 aL0 = *(const s16x8*)(AsL + (m0w + r16) * 40 + quad * 8);
    s16x8 aL1 = *(const s16x8*)(AsL + (m0w + 16 + r16) * 40 + quad * 8);
    s16x8 bH0 = *(const s16x8*)(BsH + (n0w + r16) * 40 + quad * 8);
    s16x8 bH1 = *(const s16x8*)(BsH + (n0w + 16 + r16) * 40 + quad * 8);
    s16x8 bL0 = *(const s16x8*)(BsL + (n0w + r16) * 40 + quad * 8);
    s16x8 bL1 = *(const s16x8*)(BsL + (n0w + 16 + r16) * 40 + quad * 8);
    acc00 = __builtin_amdgcn_mfma_f32_16x16x32_bf16(aH0, bH0, acc00, 0, 0, 0);
    acc00 = __builtin_amdgcn_mfma_f32_16x16x32_bf16(aH0, bL0, acc00, 0, 0, 0);
    acc00 = __builtin_amdgcn_mfma_f32_16x16x32_bf16(aL0, bH0, acc00, 0, 0, 0);
    acc01 = __builtin_amdgcn_mfma_f32_16x16x32_bf16(aH0, bH1, acc01, 0, 0, 0);
    acc01 = __builtin_amdgcn_mfma_f32_16x16x32_bf16(aH0, bL1, acc01, 0, 0, 0);
    acc01 = __builtin_amdgcn_mfma_f32_16x16x32_bf16(aL0, bH1, acc01, 0, 0, 0);
    acc10 = __builtin_amdgcn_mfma_f32_16x16x32_bf16(aH1, bH0, acc10, 0, 0, 0);
    acc10 = __builtin_amdgcn_mfma_f32_16x16x32_bf16(aH1, bL0, acc10, 0, 0, 0);
    acc10 = __builtin_amdgcn_mfma_f32_16x16x32_bf16(aL1, bH0, acc10, 0, 0, 0);
    acc11 = __builtin_amdgcn_mfma_f32_16x16x32_bf16(aH1, bH1, acc11, 0, 0, 0);
    acc11 = __builtin_amdgcn_mfma_f32_16x16x32_bf16(aH1, bL1, acc11, 0, 0, 0);
    acc11 = __builtin_amdgcn_mfma_f32_16x16x32_bf16(aL1, bH1, acc11, 0, 0, 0);
    __syncthreads();
  }
  // ---- epilogue: exp + scatter. C/D: col = lane&15, row = quad*4 + reg ----
  float* qe = outbuf;            // [1024][512]
  float* kep = outbuf + 524288;  // [4][512][256]
  const int mq = quad * 4;
#pragma unroll
  for (int f = 0; f < 4; ++f) {
    const int fi = f >> 1, fj = f & 1;
    f32x4 ac = (f == 0) ? acc00 : (f == 1) ? acc01 : (f == 2) ? acc10 : acc11;
    const int nn = N0 + n0w + fj * 16 + r16;
    float i2 = 0.f;
    if (z) i2 = 0.5f / scale[nn];
#pragma unroll
    for (int r = 0; r < 4; ++r) {
      const int mm = M0 + m0w + fi * 16 + mq + r;
      float e = __expf(2.f * ac[r]);
      if (z == 0) {
        qe[mm * 512 + nn] = e;
      } else {
        const int bb = mm >> 8, kl = mm & 255;
        kep[bb * 131072 + nn * 256 + kl] = e * i2;
      }
    }
  }
}

// ---------- K2a: scores + softmax -> attn region only ----------------------
// 1 block = (b, 4 q rows). grid 256, block 512.
__global__ __launch_bounds__(512) void k2a_attn(
    const float* __restrict__ qe, const float* __restrict__ kep,
    const float* __restrict__ scale, float* __restrict__ attn) {
  const int b = blockIdx.x >> 6;
  const int qbase = (blockIdx.x & 63) * 4;
  const int tid = threadIdx.x;
  __shared__ __align__(16) float qh[512 * 2 * 4];  // [u][half]{qe0,qe1,ie2,pad}
  __shared__ __align__(16) float ps[256 * 4];      // [k][qi]

  for (int idx = tid; idx < 1024; idx += 512) {
    int u = idx >> 1, h = idx & 1;
    float* p = &qh[(u * 2 + h) * 4];
    p[0] = qe[(b * 256 + qbase + 2 * h) * 512 + u];
    p[1] = qe[(b * 256 + qbase + 2 * h + 1) * 512 + u];
    p[2] = 0.5f / scale[u];
    p[3] = 0.f;
  }
  __syncthreads();

  const int k = tid & 255, half = tid >> 8;
  const float* kb = kep + b * 131072;
  const float4* qhv = (const float4*)qh;
  float s0 = 0.f, s1 = 0.f;
#pragma unroll 8
  for (int u = 0; u < 512; ++u) {
    float kv = kb[u * 256 + k];     // coalesced, L2-resident
    float4 qq = qhv[u * 2 + half];  // wave-uniform LDS broadcast
    s0 += __builtin_amdgcn_rcpf(fmaf(qq.x, kv, qq.z));
    s1 += __builtin_amdgcn_rcpf(fmaf(qq.y, kv, qq.z));
  }
  ps[k * 4 + 2 * half] = s0;  // softmax score = -acc (S cancels)
  ps[k * 4 + 2 * half + 1] = s1;
  __syncthreads();

  const int w = tid >> 6, lane = tid & 63;
  if (w < 4) {  // wave w: softmax for q-row qbase+w
    float x0 = -ps[(lane)*4 + w], x1 = -ps[(lane + 64) * 4 + w];
    float x2 = -ps[(lane + 128) * 4 + w], x3 = -ps[(lane + 192) * 4 + w];
    float m = fmaxf(fmaxf(x0, x1), fmaxf(x2, x3));
    for (int off = 32; off; off >>= 1) m = fmaxf(m, __shfl_xor(m, off));
    float e0 = __expf(x0 - m), e1 = __expf(x1 - m);
    float e2 = __expf(x2 - m), e3 = __expf(x3 - m);
    float t = e0 + e1 + e2 + e3;
    for (int off = 32; off; off >>= 1) t += __shfl_xor(t, off);
    float inv = 1.0f / t;
    float* ar = attn + (b * 256 + qbase + w) * 256;
    ar[lane] = e0 * inv;
    ar[lane + 64] = e1 * inv;
    ar[lane + 128] = e2 * inv;
    ar[lane + 192] = e3 * inv;
  }
}

// ---------- K2b: ctx = attn @ value, overwrites ctx region -----------------
// grid (2, 32, 4): d-half, 8 q-rows, batch. block 256.
__global__ __launch_bounds__(256) void k2b_ctx(
    const float* __restrict__ attn, const float* __restrict__ value,
    float* __restrict__ ctx) {
  const int dh = blockIdx.x, q0 = blockIdx.y * 8, b = blockIdx.z;
  const int tid = threadIdx.x;
  __shared__ __align__(16) float pl[256 * 8];  // [k][r]
#pragma unroll
  for (int r = 0; r < 8; ++r)
    pl[tid * 8 + r] = attn[(b * 256 + q0 + r) * 256 + tid];
  __syncthreads();
  const float2* v2 = (const float2*)value + b * 131072 + dh * 256 + tid;
  const float4* pl4 = (const float4*)pl;
  float2 acc[8];
#pragma unroll
  for (int r = 0; r < 8; ++r) acc[r] = make_float2(0.f, 0.f);
#pragma unroll 4
  for (int kk = 0; kk < 256; ++kk) {
    float2 v = v2[kk * 512];
    float4 pa = pl4[kk * 2], pb = pl4[kk * 2 + 1];  // LDS broadcast b128
    acc[0].x = fmaf(pa.x, v.x, acc[0].x); acc[0].y = fmaf(pa.x, v.y, acc[0].y);
    acc[1].x = fmaf(pa.y, v.x, acc[1].x); acc[1].y = fmaf(pa.y, v.y, acc[1].y);
    acc[2].x = fmaf(pa.z, v.x, acc[2].x); acc[2].y = fmaf(pa.z, v.y, acc[2].y);
    acc[3].x = fmaf(pa.w, v.x, acc[3].x); acc[3].y = fmaf(pa.w, v.y, acc[3].y);
    acc[4].x = fmaf(pb.x, v.x, acc[4].x); acc[4].y = fmaf(pb.x, v.y, acc[4].y);
    acc[5].x = fmaf(pb.y, v.x, acc[5].x); acc[5].y = fmaf(pb.y, v.y, acc[5].y);
    acc[6].x = fmaf(pb.z, v.x, acc[6].x); acc[6].y = fmaf(pb.z, v.y, acc[6].y);
    acc[7].x = fmaf(pb.w, v.x, acc[7].x); acc[7].y = fmaf(pb.w, v.y, acc[7].y);
  }
  float2* c2 = (float2*)ctx;
#pragma unroll
  for (int r = 0; r < 8; ++r)
    c2[(b * 256 + q0 + r) * 512 + dh * 256 + tid] = acc[r];
}

extern "C" void kernel_launch(void* const* d_in, const int* in_sizes, int n_in,
                              void* d_out, int out_size, void* d_ws, size_t ws_size,
                              hipStream_t stream) {
  (void)d_ws; (void)ws_size;  // deliberately unused — see header comment
  const float *query = nullptr, *value = nullptr, *Wq = nullptr, *Wk = nullptr,
              *scale = nullptr;
  for (int i = 0; i < n_in; ++i) {
    int s = in_sizes[i];
    if (s == 1048576) { if (!query) query = (const float*)d_in[i]; else if (!value) value = (const float*)d_in[i]; }
    else if (s == 524288) { if (!Wq) Wq = (const float*)d_in[i]; else if (!Wk) Wk = (const float*)d_in[i]; }
    else if (s == 512) { scale = (const float*)d_in[i]; }
  }
  float* ob = (float*)d_out;
  k1_mfma<<<dim3(8, 16, 2), 256, 0, stream>>>(query, value, Wq, Wk, scale, ob);
  k2a_attn<<<dim3(256), 512, 0, stream>>>(ob, ob + 524288, scale, ob + 1048576);
  k2b_ctx<<<dim3(2, 32, 4), 256, 0, stream>>>(ob + 1048576, value, ob);
}

// Round 6
// 140.563 us; speedup vs baseline: 1.5596x; 1.0793x over previous
//
#include <hip/hip_runtime.h>

// BahdanauAttention on MI355X — fp32 in/out. Scratch inside d_out.
//
// d_out float layout: ctx [0, 1048576), attn [1048576, 1310720).
// Phases 1-2 use ctx region as scratch:
//   qe  at [0,      524288): [1024][512]   e^{2*qproj}
//   kep at [524288,1048576): [4][512][256] e^{2*kproj} * ie2[u], ie2=0.5/scale
// Phase 3 (k2b) overwrites ctx region with the final context.
//
// Math: tanh(x) = 1 - 2/(e^{2x}+1); score = S - sum_u 2*scale_u/(E+1),
// S = sum(scale) cancels in softmax. term = rcp(qe*kep + ie2).
//
// k1 v2 (round 5): v1 was latency-bound (1 wave/SIMD, 2 barriers/iter, no
// prefetch -> 59.5 us). Now: 512-thread blocks (2 waves/SIMD), K split
// between wave halves (LDS reduction at end), register prefetch of next
// tile, double-buffered LDS -> 1 barrier/iter. Same exact-split bf16 MFMA
// (hi*hi + hi*lo + lo*hi), same verified 16x16x32 fragment layouts.

typedef unsigned int u32;
typedef unsigned short u16;
typedef __attribute__((ext_vector_type(8))) short s16x8;
typedef __attribute__((ext_vector_type(4))) float f32x4;

__device__ __forceinline__ void split8(const float* fs, uint4& h, uint4& l) {
  u32 hh[4], ll[4];
#pragma unroll
  for (int p = 0; p < 4; ++p) {
    u32 u0 = __float_as_uint(fs[2 * p]);
    u32 u1 = __float_as_uint(fs[2 * p + 1]);
    hh[p] = (u0 >> 16) | (u1 & 0xffff0000u);
    float l0 = fs[2 * p] - __uint_as_float(u0 & 0xffff0000u);
    float l1 = fs[2 * p + 1] - __uint_as_float(u1 & 0xffff0000u);
    ll[p] = (__float_as_uint(l0) >> 16) | (__float_as_uint(l1) & 0xffff0000u);
  }
  h = make_uint4(hh[0], hh[1], hh[2], hh[3]);
  l = make_uint4(ll[0], ll[1], ll[2], ll[3]);
}

// ---------- K1 v2: split-bf16 MFMA projections + exp epilogue --------------
// grid (8, 16, 2), block 512. z=0: query->qe ; z=1: value->kep (transposed).
// 8 waves: pos = w&3 -> 32x32 output quadrant; kh = w>>2 -> K half.
#define LSTR 72  // u16 row stride (144 B: 16B-aligned, non-pow2 banks)
__global__ __launch_bounds__(512) void k1_mfma(
    const float* __restrict__ query, const float* __restrict__ value,
    const float* __restrict__ Wq, const float* __restrict__ Wk,
    const float* __restrict__ scale, float* __restrict__ outbuf) {
  const int z = blockIdx.z;
  const float* X = z ? value : query;  // [1024][1024]
  const float* W = z ? Wk : Wq;        // [1024][512]
  const int M0 = blockIdx.y * 64, N0 = blockIdx.x * 64;
  // [buf][{AsH,AsL,BsH,BsL}][64][LSTR] u16
  __shared__ __align__(16) u16 sm[2 * 4 * 64 * LSTR];
  const int tid = threadIdx.x;
  const int lane = tid & 63, w = tid >> 6;
  const int pos = w & 3, kh = w >> 2;
  const int wm = (pos & 1) * 32, wn = (pos >> 1) * 32;
  const int quad = lane >> 4, r16 = lane & 15;
  const int fko = kh * 32 + quad * 8;  // frag k offset within 64-col stage

  // staging ownership
  const int arow = tid >> 3, as8 = (tid & 7) * 8;          // A: 64r x 8seg
  const int aoff = (as8 < 32) ? as8 : (480 + as8);         // k-chunk mapping
  const int bu = tid & 63, bks = tid >> 6;                 // B: 64u x 8seg
  const int boff = (bks < 4) ? (bks * 8) : (480 + bks * 8);
  const float* aP = X + (M0 + arow) * 1024 + aoff;
  const float* bP = W + boff * 512 + N0 + bu;

  f32x4 acc[4];
#pragma unroll
  for (int f = 0; f < 4; ++f) acc[f] = (f32x4){0.f, 0.f, 0.f, 0.f};

  // prefetch tile 0
  float4 pa0 = *(const float4*)(aP);
  float4 pa1 = *(const float4*)(aP + 4);
  float pb[8];
#pragma unroll
  for (int c = 0; c < 8; ++c) pb[c] = bP[c * 512];

  for (int i = 0; i < 16; ++i) {
    u16* base = sm + (i & 1) * 4 * 64 * LSTR;
    u16* AsH = base;
    u16* AsL = base + 64 * LSTR;
    u16* BsH = base + 2 * 64 * LSTR;
    u16* BsL = base + 3 * 64 * LSTR;
    {  // stage prefetched regs -> LDS (split hi/lo)
      float fa[8] = {pa0.x, pa0.y, pa0.z, pa0.w, pa1.x, pa1.y, pa1.z, pa1.w};
      uint4 h, l;
      split8(fa, h, l);
      *(uint4*)(AsH + arow * LSTR + as8) = h;
      *(uint4*)(AsL + arow * LSTR + as8) = l;
      split8(pb, h, l);
      *(uint4*)(BsH + bu * LSTR + bks * 8) = h;
      *(uint4*)(BsL + bu * LSTR + bks * 8) = l;
    }
    __syncthreads();
    if (i < 15) {  // prefetch next tile while compute runs
      pa0 = *(const float4*)(aP + (i + 1) * 32);
      pa1 = *(const float4*)(aP + (i + 1) * 32 + 4);
#pragma unroll
      for (int c = 0; c < 8; ++c) pb[c] = bP[((i + 1) * 32 + c) * 512];
    }
    s16x8 aH0 = *(const s16x8*)(AsH + (wm + r16) * LSTR + fko);
    s16x8 aH1 = *(const s16x8*)(AsH + (wm + 16 + r16) * LSTR + fko);
    s16x8 aL0 = *(const s16x8*)(AsL + (wm + r16) * LSTR + fko);
    s16x8 aL1 = *(const s16x8*)(AsL + (wm + 16 + r16) * LSTR + fko);
    s16x8 bH0 = *(const s16x8*)(BsH + (wn + r16) * LSTR + fko);
    s16x8 bH1 = *(const s16x8*)(BsH + (wn + 16 + r16) * LSTR + fko);
    s16x8 bL0 = *(const s16x8*)(BsL + (wn + r16) * LSTR + fko);
    s16x8 bL1 = *(const s16x8*)(BsL + (wn + 16 + r16) * LSTR + fko);
    acc[0] = __builtin_amdgcn_mfma_f32_16x16x32_bf16(aH0, bH0, acc[0], 0, 0, 0);
    acc[0] = __builtin_amdgcn_mfma_f32_16x16x32_bf16(aH0, bL0, acc[0], 0, 0, 0);
    acc[0] = __builtin_amdgcn_mfma_f32_16x16x32_bf16(aL0, bH0, acc[0], 0, 0, 0);
    acc[1] = __builtin_amdgcn_mfma_f32_16x16x32_bf16(aH0, bH1, acc[1], 0, 0, 0);
    acc[1] = __builtin_amdgcn_mfma_f32_16x16x32_bf16(aH0, bL1, acc[1], 0, 0, 0);
    acc[1] = __builtin_amdgcn_mfma_f32_16x16x32_bf16(aL0, bH1, acc[1], 0, 0, 0);
    acc[2] = __builtin_amdgcn_mfma_f32_16x16x32_bf16(aH1, bH0, acc[2], 0, 0, 0);
    acc[2] = __builtin_amdgcn_mfma_f32_16x16x32_bf16(aH1, bL0, acc[2], 0, 0, 0);
    acc[2] = __builtin_amdgcn_mfma_f32_16x16x32_bf16(aL1, bH0, acc[2], 0, 0, 0);
    acc[3] = __builtin_amdgcn_mfma_f32_16x16x32_bf16(aH1, bH1, acc[3], 0, 0, 0);
    acc[3] = __builtin_amdgcn_mfma_f32_16x16x32_bf16(aH1, bL1, acc[3], 0, 0, 0);
    acc[3] = __builtin_amdgcn_mfma_f32_16x16x32_bf16(aL1, bH1, acc[3], 0, 0, 0);
    __syncthreads();  // frag reads done before next iter's stage overwrites
  }

  // ---- cross-kh reduction through LDS ----
  float* red = (float*)sm;  // 16 KB, reuses staging LDS
  if (kh == 1) {
#pragma unroll
    for (int f = 0; f < 4; ++f)
      *(f32x4*)&red[((pos * 4 + f) * 64 + lane) * 4] = acc[f];
  }
  __syncthreads();
  if (kh == 0) {
    float* qe = outbuf;            // [1024][512]
    float* kep = outbuf + 524288;  // [4][512][256]
    const int mq = quad * 4;
#pragma unroll
    for (int f = 0; f < 4; ++f) {
      f32x4 o = *(const f32x4*)&red[((pos * 4 + f) * 64 + lane) * 4];
      f32x4 ac = acc[f];
      ac += o;
      const int fi = f >> 1, fj = f & 1;
      const int nn = N0 + wn + fj * 16 + r16;  // C/D: col = lane&15
      float i2 = 0.f;
      if (z) i2 = 0.5f / scale[nn];
#pragma unroll
      for (int r = 0; r < 4; ++r) {
        const int mm = M0 + wm + fi * 16 + mq + r;  // C/D: row = quad*4+reg
        float e = __expf(2.f * ac[r]);
        if (z == 0) {
          qe[mm * 512 + nn] = e;
        } else {
          const int bb = mm >> 8, kl = mm & 255;
          kep[bb * 131072 + nn * 256 + kl] = e * i2;
        }
      }
    }
  }
}

// ---------- K2a: scores + softmax -> attn region only ----------------------
// 1 block = (b, 4 q rows). grid 256, block 512.
__global__ __launch_bounds__(512) void k2a_attn(
    const float* __restrict__ qe, const float* __restrict__ kep,
    const float* __restrict__ scale, float* __restrict__ attn) {
  const int b = blockIdx.x >> 6;
  const int qbase = (blockIdx.x & 63) * 4;
  const int tid = threadIdx.x;
  __shared__ __align__(16) float qh[512 * 2 * 4];  // [u][half]{qe0,qe1,ie2,pad}
  __shared__ __align__(16) float ps[256 * 4];      // [k][qi]

  for (int idx = tid; idx < 1024; idx += 512) {
    int u = idx >> 1, h = idx & 1;
    float* p = &qh[(u * 2 + h) * 4];
    p[0] = qe[(b * 256 + qbase + 2 * h) * 512 + u];
    p[1] = qe[(b * 256 + qbase + 2 * h + 1) * 512 + u];
    p[2] = 0.5f / scale[u];
    p[3] = 0.f;
  }
  __syncthreads();

  const int k = tid & 255, half = tid >> 8;
  const float* kb = kep + b * 131072;
  const float4* qhv = (const float4*)qh;
  float s0 = 0.f, s1 = 0.f;
#pragma unroll 8
  for (int u = 0; u < 512; ++u) {
    float kv = kb[u * 256 + k];     // coalesced, L2-resident
    float4 qq = qhv[u * 2 + half];  // wave-uniform LDS broadcast
    s0 += __builtin_amdgcn_rcpf(fmaf(qq.x, kv, qq.z));
    s1 += __builtin_amdgcn_rcpf(fmaf(qq.y, kv, qq.z));
  }
  ps[k * 4 + 2 * half] = s0;  // softmax score = -acc (S cancels)
  ps[k * 4 + 2 * half + 1] = s1;
  __syncthreads();

  const int w = tid >> 6, lane = tid & 63;
  if (w < 4) {  // wave w: softmax for q-row qbase+w
    float x0 = -ps[(lane)*4 + w], x1 = -ps[(lane + 64) * 4 + w];
    float x2 = -ps[(lane + 128) * 4 + w], x3 = -ps[(lane + 192) * 4 + w];
    float m = fmaxf(fmaxf(x0, x1), fmaxf(x2, x3));
    for (int off = 32; off; off >>= 1) m = fmaxf(m, __shfl_xor(m, off));
    float e0 = __expf(x0 - m), e1 = __expf(x1 - m);
    float e2 = __expf(x2 - m), e3 = __expf(x3 - m);
    float t = e0 + e1 + e2 + e3;
    for (int off = 32; off; off >>= 1) t += __shfl_xor(t, off);
    float inv = 1.0f / t;
    float* ar = attn + (b * 256 + qbase + w) * 256;
    ar[lane] = e0 * inv;
    ar[lane + 64] = e1 * inv;
    ar[lane + 128] = e2 * inv;
    ar[lane + 192] = e3 * inv;
  }
}

// ---------- K2b: ctx = attn @ value, overwrites ctx region -----------------
// grid (2, 32, 4): d-half, 8 q-rows, batch. block 256.
__global__ __launch_bounds__(256) void k2b_ctx(
    const float* __restrict__ attn, const float* __restrict__ value,
    float* __restrict__ ctx) {
  const int dh = blockIdx.x, q0 = blockIdx.y * 8, b = blockIdx.z;
  const int tid = threadIdx.x;
  __shared__ __align__(16) float pl[256 * 8];  // [k][r]
#pragma unroll
  for (int r = 0; r < 8; ++r)
    pl[tid * 8 + r] = attn[(b * 256 + q0 + r) * 256 + tid];
  __syncthreads();
  const float2* v2 = (const float2*)value + b * 131072 + dh * 256 + tid;
  const float4* pl4 = (const float4*)pl;
  float2 acc[8];
#pragma unroll
  for (int r = 0; r < 8; ++r) acc[r] = make_float2(0.f, 0.f);
#pragma unroll 4
  for (int kk = 0; kk < 256; ++kk) {
    float2 v = v2[kk * 512];
    float4 pa = pl4[kk * 2], pb = pl4[kk * 2 + 1];  // LDS broadcast b128
    acc[0].x = fmaf(pa.x, v.x, acc[0].x); acc[0].y = fmaf(pa.x, v.y, acc[0].y);
    acc[1].x = fmaf(pa.y, v.x, acc[1].x); acc[1].y = fmaf(pa.y, v.y, acc[1].y);
    acc[2].x = fmaf(pa.z, v.x, acc[2].x); acc[2].y = fmaf(pa.z, v.y, acc[2].y);
    acc[3].x = fmaf(pa.w, v.x, acc[3].x); acc[3].y = fmaf(pa.w, v.y, acc[3].y);
    acc[4].x = fmaf(pb.x, v.x, acc[4].x); acc[4].y = fmaf(pb.x, v.y, acc[4].y);
    acc[5].x = fmaf(pb.y, v.x, acc[5].x); acc[5].y = fmaf(pb.y, v.y, acc[5].y);
    acc[6].x = fmaf(pb.z, v.x, acc[6].x); acc[6].y = fmaf(pb.z, v.y, acc[6].y);
    acc[7].x = fmaf(pb.w, v.x, acc[7].x); acc[7].y = fmaf(pb.w, v.y, acc[7].y);
  }
  float2* c2 = (float2*)ctx;
#pragma unroll
  for (int r = 0; r < 8; ++r)
    c2[(b * 256 + q0 + r) * 512 + dh * 256 + tid] = acc[r];
}

extern "C" void kernel_launch(void* const* d_in, const int* in_sizes, int n_in,
                              void* d_out, int out_size, void* d_ws, size_t ws_size,
                              hipStream_t stream) {
  (void)d_ws; (void)ws_size;  // unused; scratch lives in d_out
  const float *query = nullptr, *value = nullptr, *Wq = nullptr, *Wk = nullptr,
              *scale = nullptr;
  for (int i = 0; i < n_in; ++i) {
    int s = in_sizes[i];
    if (s == 1048576) { if (!query) query = (const float*)d_in[i]; else if (!value) value = (const float*)d_in[i]; }
    else if (s == 524288) { if (!Wq) Wq = (const float*)d_in[i]; else if (!Wk) Wk = (const float*)d_in[i]; }
    else if (s == 512) { scale = (const float*)d_in[i]; }
  }
  float* ob = (float*)d_out;
  k1_mfma<<<dim3(8, 16, 2), 512, 0, stream>>>(query, value, Wq, Wk, scale, ob);
  k2a_attn<<<dim3(256), 512, 0, stream>>>(ob, ob + 524288, scale, ob + 1048576);
  k2b_ctx<<<dim3(2, 32, 4), 256, 0, stream>>>(ob + 1048576, value, ob);
}

// Round 7
// 138.935 us; speedup vs baseline: 1.5779x; 1.0117x over previous
//
#include <hip/hip_runtime.h>

// BahdanauAttention on MI355X — fp32 in/out. Scratch inside d_out.
//
// d_out float layout: ctx [0, 1048576), attn [1048576, 1310720).
// Phases 1-2 use ctx region as scratch:
//   qe  at [0,      524288): [1024][512]   e^{2*qproj}
//   kep at [524288,1048576): [4][512][256] e^{2*kproj} * ie2[u], ie2=0.5/scale
// Phase 3 (k2b) overwrites ctx region with the final context.
//
// Math: tanh(x) = 1 - 2/(e^{2x}+1); score = S - sum_u 2*scale_u/(E+1),
// S = sum(scale) cancels in softmax. term = rcp(qe*kep + ie2).
//
// k1 v3 (round 6): v2 was split-VALU + LDS-b128 bound with 1 block/CU and
// barrier-serialized staging. v3 is LDS-FREE and BARRIER-FREE: MFMA frags
// load directly from global (A: 2 float4/lane; B: 8 coalesced strided
// dwords/frag), exact hi/lo split in-register via v_perm_b32. 512 blocks
// (2/CU). Same exact-split math (hi*hi + hi*lo + lo*hi), same verified
// 16x16x32 layouts (A/B: lane(r16,quad)=[r16][quad*8+j]; C/D: col=lane&15,
// row=quad*4+reg).

typedef unsigned int u32;
typedef unsigned short u16;
typedef __attribute__((ext_vector_type(8))) short s16x8;
typedef __attribute__((ext_vector_type(4))) float f32x4;
typedef __attribute__((ext_vector_type(4))) u32 u32x4;

union v4cast { u32x4 u; s16x8 s; };

// exact split of 8 fp32 -> bf16 hi (trunc) + bf16 lo (trunc of x - hi)
__device__ __forceinline__ void split8(const float* f, s16x8& h, s16x8& l) {
  v4cast hv, lv;
#pragma unroll
  for (int p = 0; p < 4; ++p) {
    u32 u0 = __float_as_uint(f[2 * p]);
    u32 u1 = __float_as_uint(f[2 * p + 1]);
    hv.u[p] = __builtin_amdgcn_perm(u1, u0, 0x07060302u);  // [u0.hi16,u1.hi16]
    float l0 = f[2 * p] - __uint_as_float(u0 & 0xffff0000u);
    float l1 = f[2 * p + 1] - __uint_as_float(u1 & 0xffff0000u);
    lv.u[p] = __builtin_amdgcn_perm(__float_as_uint(l1), __float_as_uint(l0),
                                    0x07060302u);
  }
  h = hv.s;
  l = lv.s;
}

// ---------- K1 v3: LDS-free split-bf16 MFMA projections + exp epilogue -----
// grid (16, 16, 2), block 256 = 4 waves. Block tile: 64 m x 32 n; wave:
// 16 m x 32 n. K loop: step 32, 6 MFMA/wave/iter.
__global__ __launch_bounds__(256, 2) void k1_mfma(
    const float* __restrict__ query, const float* __restrict__ value,
    const float* __restrict__ Wq, const float* __restrict__ Wk,
    const float* __restrict__ scale, float* __restrict__ outbuf) {
  const int z = blockIdx.z;
  const float* X = z ? value : query;  // [1024][1024]
  const float* W = z ? Wk : Wq;        // [1024][512]
  const int M0 = blockIdx.y * 64, N0 = blockIdx.x * 32;
  const int lane = threadIdx.x & 63, wv = threadIdx.x >> 6;
  const int quad = lane >> 4, r16 = lane & 15;
  const int m = M0 + wv * 16 + r16;                 // A-frag row
  const float* aP = X + m * 1024 + quad * 8;        // + kb
  const float* bP = W + (quad * 8) * 512 + N0 + r16;  // + (kb+j)*512 (+16)

  f32x4 acc0 = {0.f, 0.f, 0.f, 0.f}, acc1 = {0.f, 0.f, 0.f, 0.f};
#pragma unroll 2
  for (int kb = 0; kb < 1024; kb += 32) {
    float4 xa = *(const float4*)(aP + kb);
    float4 xb = *(const float4*)(aP + kb + 4);
    float fb0[8], fb1[8];
    const float* bk = bP + kb * 512;
#pragma unroll
    for (int j = 0; j < 8; ++j) {
      fb0[j] = bk[j * 512];
      fb1[j] = bk[j * 512 + 16];
    }
    float fa[8] = {xa.x, xa.y, xa.z, xa.w, xb.x, xb.y, xb.z, xb.w};
    s16x8 aH, aL, bH0, bL0, bH1, bL1;
    split8(fa, aH, aL);
    split8(fb0, bH0, bL0);
    split8(fb1, bH1, bL1);
    acc0 = __builtin_amdgcn_mfma_f32_16x16x32_bf16(aH, bH0, acc0, 0, 0, 0);
    acc0 = __builtin_amdgcn_mfma_f32_16x16x32_bf16(aH, bL0, acc0, 0, 0, 0);
    acc0 = __builtin_amdgcn_mfma_f32_16x16x32_bf16(aL, bH0, acc0, 0, 0, 0);
    acc1 = __builtin_amdgcn_mfma_f32_16x16x32_bf16(aH, bH1, acc1, 0, 0, 0);
    acc1 = __builtin_amdgcn_mfma_f32_16x16x32_bf16(aH, bL1, acc1, 0, 0, 0);
    acc1 = __builtin_amdgcn_mfma_f32_16x16x32_bf16(aL, bH1, acc1, 0, 0, 0);
  }

  // epilogue: C/D col = lane&15 (-> n), row = quad*4 + reg (-> m within 16)
  float* qe = outbuf;            // [1024][512]
  float* kep = outbuf + 524288;  // [4][512][256]
  const int mq = quad * 4;
#pragma unroll
  for (int f = 0; f < 2; ++f) {
    f32x4 ac = f ? acc1 : acc0;
    const int nn = N0 + f * 16 + r16;
    float i2 = 0.f;
    if (z) i2 = 0.5f / scale[nn];
#pragma unroll
    for (int r = 0; r < 4; ++r) {
      const int mm = M0 + wv * 16 + mq + r;
      float e = __expf(2.f * ac[r]);
      if (z == 0) {
        qe[mm * 512 + nn] = e;
      } else {
        const int bb = mm >> 8, kl = mm & 255;
        kep[bb * 131072 + nn * 256 + kl] = e * i2;
      }
    }
  }
}

// ---------- K2a v2: scores + softmax. 1 block = (b, 2 q rows) --------------
// grid 512, block 256. thread: 1 k, both q rows.
__global__ __launch_bounds__(256) void k2a_attn(
    const float* __restrict__ qe, const float* __restrict__ kep,
    const float* __restrict__ scale, float* __restrict__ attn) {
  const int b = blockIdx.x >> 7;
  const int q0 = (blockIdx.x & 127) * 2;
  const int tid = threadIdx.x;
  __shared__ __align__(16) float4 qh[512];     // [u]{qe_q0, qe_q1, ie2, pad}
  __shared__ __align__(16) float ps[2 * 256];  // [q][k]

  const float* qrow = qe + (b * 256 + q0) * 512;
#pragma unroll
  for (int i = 0; i < 2; ++i) {
    int u = tid + i * 256;
    float4 v;
    v.x = qrow[u];
    v.y = qrow[512 + u];
    v.z = 0.5f / scale[u];
    v.w = 0.f;
    qh[u] = v;
  }
  __syncthreads();

  const int k = tid;
  const float* kb = kep + b * 131072 + k;
  float s0 = 0.f, s1 = 0.f;
#pragma unroll 16
  for (int u = 0; u < 512; ++u) {
    float kv = kb[u * 256];  // coalesced, L2-resident
    float4 qq = qh[u];       // wave-uniform LDS broadcast
    s0 += __builtin_amdgcn_rcpf(fmaf(qq.x, kv, qq.z));
    s1 += __builtin_amdgcn_rcpf(fmaf(qq.y, kv, qq.z));
  }
  ps[k] = s0;  // softmax score = -acc (S cancels)
  ps[256 + k] = s1;
  __syncthreads();

  const int w = tid >> 6, lane = tid & 63;
  if (w < 2) {  // wave w: softmax for q-row q0+w
    float x0 = -ps[w * 256 + lane], x1 = -ps[w * 256 + lane + 64];
    float x2 = -ps[w * 256 + lane + 128], x3 = -ps[w * 256 + lane + 192];
    float m = fmaxf(fmaxf(x0, x1), fmaxf(x2, x3));
    for (int off = 32; off; off >>= 1) m = fmaxf(m, __shfl_xor(m, off));
    float e0 = __expf(x0 - m), e1 = __expf(x1 - m);
    float e2 = __expf(x2 - m), e3 = __expf(x3 - m);
    float t = e0 + e1 + e2 + e3;
    for (int off = 32; off; off >>= 1) t += __shfl_xor(t, off);
    float inv = 1.0f / t;
    float* ar = attn + (b * 256 + q0 + w) * 256;
    ar[lane] = e0 * inv;
    ar[lane + 64] = e1 * inv;
    ar[lane + 128] = e2 * inv;
    ar[lane + 192] = e3 * inv;
  }
}

// ---------- K2b v2: ctx = attn @ value ------------------------------------
// grid (2, 64, 4): d-half, 4 q-rows, batch. block 256, thread: 1 float2 x 4q.
__global__ __launch_bounds__(256) void k2b_ctx(
    const float* __restrict__ attn, const float* __restrict__ value,
    float* __restrict__ ctx) {
  const int dh = blockIdx.x, q0 = blockIdx.y * 4, b = blockIdx.z;
  const int tid = threadIdx.x;
  __shared__ __align__(16) float pl[256 * 4];  // [k][r]
#pragma unroll
  for (int r = 0; r < 4; ++r)
    pl[tid * 4 + r] = attn[(b * 256 + q0 + r) * 256 + tid];
  __syncthreads();
  const float2* v2 = (const float2*)value + b * 131072 + dh * 256 + tid;
  const float4* pl4 = (const float4*)pl;
  float2 a0 = {0.f, 0.f}, a1 = a0, a2 = a0, a3 = a0;
#pragma unroll 8
  for (int kk = 0; kk < 256; ++kk) {
    float2 v = v2[kk * 512];
    float4 p = pl4[kk];  // LDS broadcast b128
    a0.x = fmaf(p.x, v.x, a0.x); a0.y = fmaf(p.x, v.y, a0.y);
    a1.x = fmaf(p.y, v.x, a1.x); a1.y = fmaf(p.y, v.y, a1.y);
    a2.x = fmaf(p.z, v.x, a2.x); a2.y = fmaf(p.z, v.y, a2.y);
    a3.x = fmaf(p.w, v.x, a3.x); a3.y = fmaf(p.w, v.y, a3.y);
  }
  float2* c2 = (float2*)ctx;
  const int base = (b * 256 + q0) * 512 + dh * 256 + tid;
  c2[base] = a0;
  c2[base + 512] = a1;
  c2[base + 1024] = a2;
  c2[base + 1536] = a3;
}

extern "C" void kernel_launch(void* const* d_in, const int* in_sizes, int n_in,
                              void* d_out, int out_size, void* d_ws, size_t ws_size,
                              hipStream_t stream) {
  (void)d_ws; (void)ws_size;  // unused; scratch lives in d_out
  const float *query = nullptr, *value = nullptr, *Wq = nullptr, *Wk = nullptr,
              *scale = nullptr;
  for (int i = 0; i < n_in; ++i) {
    int s = in_sizes[i];
    if (s == 1048576) { if (!query) query = (const float*)d_in[i]; else if (!value) value = (const float*)d_in[i]; }
    else if (s == 524288) { if (!Wq) Wq = (const float*)d_in[i]; else if (!Wk) Wk = (const float*)d_in[i]; }
    else if (s == 512) { scale = (const float*)d_in[i]; }
  }
  float* ob = (float*)d_out;
  k1_mfma<<<dim3(16, 16, 2), 256, 0, stream>>>(query, value, Wq, Wk, scale, ob);
  k2a_attn<<<dim3(512), 256, 0, stream>>>(ob, ob + 524288, scale, ob + 1048576);
  k2b_ctx<<<dim3(2, 64, 4), 256, 0, stream>>>(ob + 1048576, value, ob);
}